// Round 8
// baseline (366.159 us; speedup 1.0000x reference)
//
#include <hip/hip_runtime.h>

// ---------------------------------------------------------------------------
// GCN 3-layer forward on MI355X — radix CSR build (256-node buckets, 2x
// parallelism) + bf16 MFMA GEMMs + 6B/edge payload (src int + norm bf16).
// Lesson R7: aggs are bound by the TCC-fetch path (~1.3 TB/s): random
// gathers warm the h-table into all 8 XCD L2s (agg32 FETCH 64MB = 12.8
// edges + 8x6.4 table warm). This round harvests build/launch/payload time.
// ---------------------------------------------------------------------------

typedef unsigned int uint32;
typedef __attribute__((ext_vector_type(8))) short bf16x8;
typedef __attribute__((ext_vector_type(4))) float f32x4;

#define G 512          // blocks in pass A / pass B
#define MAXB 512       // max coarse buckets (N <= 131072 at 256/bucket)

__device__ __forceinline__ ushort f2bf(float v) {
    uint32 u = __float_as_uint(v);
    u += 0x7fff + ((u >> 16) & 1);  // round to nearest even
    return (ushort)(u >> 16);
}
__device__ __forceinline__ uint32 pack2bf(float a, float b) {
    return (uint32)f2bf(a) | ((uint32)f2bf(b) << 16);
}
__device__ __forceinline__ float bf_lo(uint32 u) {
    return __uint_as_float(u << 16);
}
__device__ __forceinline__ float bf_hi(uint32 u) {
    return __uint_as_float(u & 0xffff0000u);
}
__device__ __forceinline__ float bfu(ushort u) {
    return __uint_as_float((uint32)u << 16);
}

// ---- pass A: per-block LDS histogram over 256-node coarse buckets ----
__global__ __launch_bounds__(512) void passA_hist_kernel(
    const int* __restrict__ dst, int* __restrict__ histG, int E, int EPB) {
    __shared__ int h[MAXB];
    const int tid = threadIdx.x, g = blockIdx.x;
    h[tid] = 0;
    __syncthreads();
    const int e0 = g * EPB, e1 = min(e0 + EPB, E);
    for (int e = e0 + tid; e < e1; e += 512) atomicAdd(&h[dst[e] >> 8], 1);
    __syncthreads();
    histG[tid * G + g] = h[tid];  // layout [bucket][block]
}

// ---- per-bucket totals (reduce histG row) ----
__global__ __launch_bounds__(512) void bucket_total_kernel(
    const int* __restrict__ histG, int* __restrict__ totals) {
    __shared__ int s[512];
    const int b = blockIdx.x, t = threadIdx.x;
    s[t] = histG[b * G + t];
    __syncthreads();
    for (int off = 256; off > 0; off >>= 1) {
        if (t < off) s[t] += s[t + off];
        __syncthreads();
    }
    if (t == 0) totals[b] = s[0];
}

// ---- exclusive scan over bucket totals -> bucketBase[NB+1] (1 block) ----
__global__ __launch_bounds__(512) void bucket_scan_kernel(
    const int* __restrict__ totals, int* __restrict__ bucketBase, int NB,
    int E) {
    __shared__ int s[512];
    const int t = threadIdx.x;
    int v = (t < NB) ? totals[t] : 0;
    s[t] = v;
    __syncthreads();
    for (int off = 1; off < 512; off <<= 1) {
        int u = (t >= off) ? s[t - off] : 0;
        __syncthreads();
        s[t] += u;
        __syncthreads();
    }
    if (t < NB) bucketBase[t] = s[t] - v;  // exclusive
    if (t == 0) bucketBase[NB] = E;
}

// ---- per-(bucket,block) write offsets: scan histG row along blocks ----
__global__ __launch_bounds__(512) void block_offs_kernel(
    const int* __restrict__ histG, const int* __restrict__ bucketBase,
    int* __restrict__ blockOffs) {
    __shared__ int s[G];
    const int b = blockIdx.x, g = threadIdx.x;
    int v = histG[b * G + g];
    s[g] = v;
    __syncthreads();
    for (int off = 1; off < G; off <<= 1) {
        int u = (g >= off) ? s[g - off] : 0;
        __syncthreads();
        s[g] += u;
        __syncthreads();
    }
    blockOffs[b * G + g] = bucketBase[b] + s[g] - v;  // exclusive along g
}

// ---- pass B: scatter edges to their coarse-bucket segment (LDS cursors) ----
__global__ __launch_bounds__(512) void passB_scatter_kernel(
    const int* __restrict__ src, const int* __restrict__ dst,
    const float* __restrict__ ew, const int* __restrict__ blockOffs,
    int2* __restrict__ tmp, int E, int EPB) {
    __shared__ int cur[MAXB];
    const int tid = threadIdx.x, g = blockIdx.x;
    cur[tid] = blockOffs[tid * G + g];
    __syncthreads();
    const int e0 = g * EPB, e1 = min(e0 + EPB, E);
    for (int e = e0 + tid; e < e1; e += 512) {
        int d = dst[e];
        int b = d >> 8;
        int pos = atomicAdd(&cur[b], 1);  // LDS atomic
        // pack: src (17 bits) | local-dst (8 bits) << 17 ; .y = ew bits
        tmp[pos] = make_int2(src[e] | ((d & 255) << 17),
                             __float_as_int(ew[e]));
    }
}

// ---- fine: per-bucket LDS counting sort -> esrc/eno + offs + dinv ----
__global__ __launch_bounds__(512) void fine_kernel(
    const int2* __restrict__ tmp, const int* __restrict__ bucketBase,
    int* __restrict__ offs, int* __restrict__ esrc, ushort* __restrict__ eno,
    float* __restrict__ dinv, int N, int E, int NB) {
    __shared__ int cnt[256];
    __shared__ int pos0[256];
    __shared__ float degf[256];
    const int t = threadIdx.x, b = blockIdx.x;
    const int base = bucketBase[b], endb = bucketBase[b + 1];
    if (t < 256) { cnt[t] = 0; degf[t] = 0.0f; }
    __syncthreads();
    for (int j = base + t; j < endb; j += 512)
        atomicAdd(&cnt[(tmp[j].x >> 17) & 255], 1);
    __syncthreads();
    int v = 0;
    if (t < 256) { v = cnt[t]; pos0[t] = v; }
    __syncthreads();
    for (int off = 1; off < 256; off <<= 1) {  // Hillis-Steele
        int u = 0;
        if (t < 256 && t >= off) u = pos0[t - off];
        __syncthreads();
        if (t < 256) pos0[t] += u;
        __syncthreads();
    }
    if (t < 256) { pos0[t] -= v; cnt[t] = 0; }  // exclusive; reset cursors
    __syncthreads();
    const int node = (b << 8) + t;
    if (t < 256 && node < N) offs[node] = base + pos0[t];
    if (b == NB - 1 && t == 0) offs[N] = E;
    for (int j = base + t; j < endb; j += 512) {
        int2 ed = tmp[j];
        int ldst = (ed.x >> 17) & 255;
        int p = base + pos0[ldst] + atomicAdd(&cnt[ldst], 1);
        esrc[p] = ed.x & 0x1FFFF;
        eno[p] = f2bf(__int_as_float(ed.y));  // ew (bf16); normed later
        atomicAdd(&degf[ldst], __int_as_float(ed.y));  // LDS float atomic
    }
    __syncthreads();
    if (t < 256 && node < N) dinv[node] = rsqrtf(1.0f + degf[t]);
}

// ---- in-place ew -> norm: eno[j] = bf16(dinv[src]*ew*dinv[dst]) ----
__global__ __launch_bounds__(256) void norm_kernel(
    const int* __restrict__ esrc, ushort* __restrict__ eno,
    const int* __restrict__ offs, const float* __restrict__ dinv, int N) {
    const int wave = threadIdx.x >> 6, lane = threadIdx.x & 63;
    const int node = blockIdx.x * 4 + wave;
    if (node >= N) return;
    const float dd = dinv[node];
    const int start = offs[node], end = offs[node + 1];
    for (int j = start + lane; j < end; j += 64) {
        float nr = dinv[esrc[j]] * bfu(eno[j]) * dd;
        eno[j] = f2bf(nr);
    }
}

// ---- all W transposes to bf16 in one launch ----
__global__ void wt_all_kernel(const float* __restrict__ W1,
                              const float* __restrict__ W2,
                              const float* __restrict__ W3,
                              ushort* __restrict__ W1T,
                              ushort* __restrict__ W2T,
                              ushort* __restrict__ W3T) {
    int i = blockIdx.x * 256 + threadIdx.x;
    if (i < 8192) {                       // W1: 128x64
        int k = i / 64, m = i % 64;
        W1T[m * 128 + k] = f2bf(W1[i]);
    } else if (i < 12288) {               // W2: 64x64
        int j = i - 8192, k = j / 64, m = j % 64;
        W2T[m * 64 + k] = f2bf(W2[j]);
    } else if (i < 14336) {               // W3: 64x32
        int j = i - 12288, k = j / 32, m = j % 32;
        W3T[m * 64 + k] = f2bf(W3[j]);
    }
}

// ---- MFMA GEMM: out_bf16[N][M] = f(in[N][K]) @ W.  4 waves x 16-row tile,
// v_mfma_f32_16x16x32_bf16; LDS rows padded +8 bf16. m89-verified layouts. ----
template <int K, int M, bool RELU, bool BIAS, bool INBF16>
__global__ __launch_bounds__(256) void gemm_mfma_kernel(
    const void* __restrict__ in_, const ushort* __restrict__ WT,
    const float* __restrict__ bias_in, ushort* __restrict__ out, int N) {
    constexpr int KP = K + 8;    // padded LDS row stride (bf16 units)
    constexpr int CCH = M / 16;  // col chunks
    __shared__ __align__(16) ushort Xl[64 * KP];
    __shared__ __align__(16) ushort Wl[M * KP];
    const int tid = threadIdx.x;
    const int node0 = blockIdx.x * 64;

    for (int i = tid; i < M * (K / 8); i += 256) {
        int row = i / (K / 8), kc = i % (K / 8);
        uint4 u = ((const uint4*)WT)[i];
        *(uint4*)&Wl[row * KP + kc * 8] = u;
    }
    if (INBF16) {
        for (int i = tid; i < 64 * (K / 8); i += 256) {
            int row = i / (K / 8), kc = i % (K / 8);
            int node = node0 + row;
            uint4 u = make_uint4(0, 0, 0, 0);
            if (node < N) {
                u = ((const uint4*)in_)[(size_t)node * (K / 8) + kc];
                if (BIAS || RELU) {
                    float v[8];
                    v[0] = bf_lo(u.x); v[1] = bf_hi(u.x);
                    v[2] = bf_lo(u.y); v[3] = bf_hi(u.y);
                    v[4] = bf_lo(u.z); v[5] = bf_hi(u.z);
                    v[6] = bf_lo(u.w); v[7] = bf_hi(u.w);
#pragma unroll
                    for (int j = 0; j < 8; ++j) {
                        if (BIAS) v[j] += bias_in[kc * 8 + j];
                        if (RELU) v[j] = fmaxf(v[j], 0.f);
                    }
                    u.x = pack2bf(v[0], v[1]); u.y = pack2bf(v[2], v[3]);
                    u.z = pack2bf(v[4], v[5]); u.w = pack2bf(v[6], v[7]);
                }
            }
            *(uint4*)&Xl[row * KP + kc * 8] = u;
        }
    } else {
        for (int i = tid; i < 64 * (K / 4); i += 256) {
            int row = i / (K / 4), kc = i % (K / 4);
            int node = node0 + row;
            uint2 p = make_uint2(0, 0);
            if (node < N) {
                float4 v = ((const float4*)in_)[(size_t)node * (K / 4) + kc];
                p.x = pack2bf(v.x, v.y);
                p.y = pack2bf(v.z, v.w);
            }
            *(uint2*)&Xl[row * KP + kc * 4] = p;
        }
    }
    __syncthreads();

    const int wv = tid >> 6, lane = tid & 63;
    const int r16 = lane & 15, quad = lane >> 4;
    f32x4 acc[CCH];
#pragma unroll
    for (int c = 0; c < CCH; ++c) acc[c] = (f32x4){0.f, 0.f, 0.f, 0.f};
#pragma unroll
    for (int kq = 0; kq < K / 32; ++kq) {
        bf16x8 a = *(const bf16x8*)
            &Xl[(wv * 16 + r16) * KP + kq * 32 + quad * 8];
#pragma unroll
        for (int c = 0; c < CCH; ++c) {
            bf16x8 b = *(const bf16x8*)
                &Wl[(c * 16 + r16) * KP + kq * 32 + quad * 8];
            acc[c] = __builtin_amdgcn_mfma_f32_16x16x32_bf16(a, b, acc[c],
                                                             0, 0, 0);
        }
    }
#pragma unroll
    for (int c = 0; c < CCH; ++c) {
#pragma unroll
        for (int r = 0; r < 4; ++r) {
            int node = node0 + wv * 16 + quad * 4 + r;
            if (node < N)
                out[(size_t)node * M + c * 16 + r16] = f2bf(acc[c][r]);
        }
    }
}

// CSR aggregate, 64-wide bf16 rows (128 B). Wave per node: 8 slots x 8
// uint4-lanes, unroll x2 => 16 rows in flight. fp32 accumulate, bf16 out.
__global__ __launch_bounds__(256) void agg64_kernel(
    const ushort* __restrict__ h, const int* __restrict__ esrc,
    const ushort* __restrict__ eno, const int* __restrict__ offs,
    const float* __restrict__ dinv, ushort* __restrict__ out, int N) {
    const int wave = threadIdx.x >> 6, lane = threadIdx.x & 63;
    const int node = blockIdx.x * 4 + wave;
    if (node >= N) return;
    const int slot = lane >> 3;  // 0..7
    const int q = lane & 7;      // uint4 index within the 128 B row
    const uint4* __restrict__ h4 = (const uint4*)h;
    const int start = offs[node], end = offs[node + 1];
    float acc[8] = {};
    int j = start + slot;
    for (; j + 8 < end; j += 16) {
        int s0 = esrc[j], s1 = esrc[j + 8];
        float n0 = bfu(eno[j]), n1 = bfu(eno[j + 8]);
        uint4 u0 = h4[(size_t)s0 * 8 + q];
        uint4 u1 = h4[(size_t)s1 * 8 + q];
        acc[0] += bf_lo(u0.x) * n0 + bf_lo(u1.x) * n1;
        acc[1] += bf_hi(u0.x) * n0 + bf_hi(u1.x) * n1;
        acc[2] += bf_lo(u0.y) * n0 + bf_lo(u1.y) * n1;
        acc[3] += bf_hi(u0.y) * n0 + bf_hi(u1.y) * n1;
        acc[4] += bf_lo(u0.z) * n0 + bf_lo(u1.z) * n1;
        acc[5] += bf_hi(u0.z) * n0 + bf_hi(u1.z) * n1;
        acc[6] += bf_lo(u0.w) * n0 + bf_lo(u1.w) * n1;
        acc[7] += bf_hi(u0.w) * n0 + bf_hi(u1.w) * n1;
    }
    if (j < end) {
        int s0 = esrc[j];
        float n0 = bfu(eno[j]);
        uint4 u0 = h4[(size_t)s0 * 8 + q];
        acc[0] += bf_lo(u0.x) * n0; acc[1] += bf_hi(u0.x) * n0;
        acc[2] += bf_lo(u0.y) * n0; acc[3] += bf_hi(u0.y) * n0;
        acc[4] += bf_lo(u0.z) * n0; acc[5] += bf_hi(u0.z) * n0;
        acc[6] += bf_lo(u0.w) * n0; acc[7] += bf_hi(u0.w) * n0;
    }
#pragma unroll
    for (int k = 0; k < 8; ++k) {
        acc[k] += __shfl_xor(acc[k], 8);
        acc[k] += __shfl_xor(acc[k], 16);
        acc[k] += __shfl_xor(acc[k], 32);
    }
    if (slot == 0) {
        float di = dinv[node];
        float sc = di * di;
        uint4 hv = h4[(size_t)node * 8 + q];
        uint4 o;
        o.x = pack2bf(acc[0] + bf_lo(hv.x) * sc, acc[1] + bf_hi(hv.x) * sc);
        o.y = pack2bf(acc[2] + bf_lo(hv.y) * sc, acc[3] + bf_hi(hv.y) * sc);
        o.z = pack2bf(acc[4] + bf_lo(hv.z) * sc, acc[5] + bf_hi(hv.z) * sc);
        o.w = pack2bf(acc[6] + bf_lo(hv.w) * sc, acc[7] + bf_hi(hv.w) * sc);
        ((uint4*)out)[(size_t)node * 8 + q] = o;
    }
}

// CSR aggregate, 32-wide bf16 rows (64 B), final layer. Wave per node:
// 16 slots x 4 lanes. Fuses self-loop, +b3, fp32 d_out, spread mean buckets.
__global__ __launch_bounds__(256) void agg32_final_kernel(
    const ushort* __restrict__ h, const int* __restrict__ esrc,
    const ushort* __restrict__ eno, const int* __restrict__ offs,
    const float* __restrict__ dinv, const float* __restrict__ b3,
    float* __restrict__ out, float* __restrict__ mean_acc, int N) {
    __shared__ float ssum[32];
    if (threadIdx.x < 32) ssum[threadIdx.x] = 0.0f;
    __syncthreads();
    const int wave = threadIdx.x >> 6, lane = threadIdx.x & 63;
    const int node = blockIdx.x * 4 + wave;
    const int slot = lane >> 2;  // 0..15
    const int q = lane & 3;      // uint4 index within the 64 B row
    const uint4* __restrict__ h4 = (const uint4*)h;
    float acc[8] = {};
    if (node < N) {
        const int start = offs[node], end = offs[node + 1];
        for (int j = start + slot; j < end; j += 16) {
            int s0 = esrc[j];
            float n0 = bfu(eno[j]);
            uint4 u0 = h4[(size_t)s0 * 4 + q];
            acc[0] += bf_lo(u0.x) * n0; acc[1] += bf_hi(u0.x) * n0;
            acc[2] += bf_lo(u0.y) * n0; acc[3] += bf_hi(u0.y) * n0;
            acc[4] += bf_lo(u0.z) * n0; acc[5] += bf_hi(u0.z) * n0;
            acc[6] += bf_lo(u0.w) * n0; acc[7] += bf_hi(u0.w) * n0;
        }
    }
#pragma unroll
    for (int k = 0; k < 8; ++k) {
        acc[k] += __shfl_xor(acc[k], 4);
        acc[k] += __shfl_xor(acc[k], 8);
        acc[k] += __shfl_xor(acc[k], 16);
        acc[k] += __shfl_xor(acc[k], 32);
    }
    if (node < N && slot == 0) {
        float di = dinv[node];
        float sc = di * di;
        uint4 hv = h4[(size_t)node * 4 + q];
        const float4* b34 = (const float4*)b3;
        float4 bA = b34[q * 2], bB = b34[q * 2 + 1];
        float4 o0, o1;
        o0.x = acc[0] + bf_lo(hv.x) * sc + bA.x;
        o0.y = acc[1] + bf_hi(hv.x) * sc + bA.y;
        o0.z = acc[2] + bf_lo(hv.y) * sc + bA.z;
        o0.w = acc[3] + bf_hi(hv.y) * sc + bA.w;
        o1.x = acc[4] + bf_lo(hv.z) * sc + bB.x;
        o1.y = acc[5] + bf_hi(hv.z) * sc + bB.y;
        o1.z = acc[6] + bf_lo(hv.w) * sc + bB.z;
        o1.w = acc[7] + bf_hi(hv.w) * sc + bB.w;
        ((float4*)out)[(size_t)node * 8 + q * 2] = o0;
        ((float4*)out)[(size_t)node * 8 + q * 2 + 1] = o1;
        int fb = q * 8;
        atomicAdd(&ssum[fb + 0], o0.x); atomicAdd(&ssum[fb + 1], o0.y);
        atomicAdd(&ssum[fb + 2], o0.z); atomicAdd(&ssum[fb + 3], o0.w);
        atomicAdd(&ssum[fb + 4], o1.x); atomicAdd(&ssum[fb + 5], o1.y);
        atomicAdd(&ssum[fb + 6], o1.z); atomicAdd(&ssum[fb + 7], o1.w);
    }
    __syncthreads();
    if (threadIdx.x < 32) {
        int bucket = blockIdx.x & 127;  // spread-bucket mean (R2 lesson)
        atomicAdd(&mean_acc[bucket * 32 + threadIdx.x], ssum[threadIdx.x]);
    }
}

__global__ void write_mean_kernel(const float* __restrict__ mean_acc,
                                  float* __restrict__ out_tail, float invN) {
    int f = threadIdx.x;
    if (f < 32) {
        float s = 0.0f;
        for (int b = 0; b < 128; ++b) s += mean_acc[b * 32 + f];
        out_tail[f] = s * invN;
    }
}

extern "C" void kernel_launch(void* const* d_in, const int* in_sizes, int n_in,
                              void* d_out, int out_size, void* d_ws,
                              size_t ws_size, hipStream_t stream) {
    const float* x  = (const float*)d_in[0];
    const int*   ei = (const int*)d_in[1];
    const float* ew = (const float*)d_in[2];
    const float* W1 = (const float*)d_in[3];
    const float* b1 = (const float*)d_in[4];
    const float* W2 = (const float*)d_in[5];
    const float* b2 = (const float*)d_in[6];
    const float* W3 = (const float*)d_in[7];
    const float* b3 = (const float*)d_in[8];

    const int N = in_sizes[0] / 128;
    const int E = in_sizes[1] / 2;
    const int* src = ei;
    const int* dst = ei + E;

    const int NB = (N + 255) >> 8;          // 256-node coarse buckets
    const int EPB = (E + G - 1) / G;        // edges per pass-A/B block

    float* out = (float*)d_out;
    char* wsp = (char*)d_ws;
    auto carve = [&](size_t bytes) {
        char* p = wsp;
        wsp += (bytes + 255) & ~(size_t)255;
        return p;
    };
    float*  dinv       = (float*)carve((size_t)N * 4);
    int*    offs       = (int*)carve((size_t)(N + 1) * 4);
    int*    bucketBase = (int*)carve((MAXB + 1) * 4);
    int*    totals     = (int*)carve(MAXB * 4);
    int*    histG      = (int*)carve((size_t)MAXB * G * 4);
    int*    blockOffs  = (int*)carve((size_t)MAXB * G * 4);
    int2*   tmp        = (int2*)carve((size_t)E * 8);
    int*    esrc       = (int*)carve((size_t)E * 4);
    ushort* eno        = (ushort*)carve((size_t)E * 2);
    ushort* hA         = (ushort*)carve((size_t)N * 64 * 2);
    ushort* hB         = (ushort*)carve((size_t)N * 64 * 2);
    ushort* W1T        = (ushort*)carve(128 * 64 * 2);
    ushort* W2T        = (ushort*)carve(64 * 64 * 2);
    ushort* W3T        = (ushort*)carve(64 * 32 * 2);
    float*  mean       = (float*)carve(128 * 32 * 4);

    const int nb_a = (N + 3) / 4;   // wave-per-node kernels: 4 nodes/block
    const int nb_g = (N + 63) / 64; // MFMA gemm: 64 nodes/block

    hipMemsetAsync(mean, 0, 128 * 32 * sizeof(float), stream);

    // ---- CSR build: LDS hist -> totals -> scan -> block offs -> bucket
    //      scatter -> fine counting sort (emits esrc/eno/offs/dinv) ----
    passA_hist_kernel<<<G, 512, 0, stream>>>(dst, histG, E, EPB);
    bucket_total_kernel<<<NB, 512, 0, stream>>>(histG, totals);
    bucket_scan_kernel<<<1, 512, 0, stream>>>(totals, bucketBase, NB, E);
    block_offs_kernel<<<NB, G, 0, stream>>>(histG, bucketBase, blockOffs);
    passB_scatter_kernel<<<G, 512, 0, stream>>>(src, dst, ew, blockOffs, tmp,
                                                E, EPB);
    fine_kernel<<<NB, 512, 0, stream>>>(tmp, bucketBase, offs, esrc, eno,
                                        dinv, N, E, NB);
    norm_kernel<<<nb_a, 256, 0, stream>>>(esrc, eno, offs, dinv, N);

    // ---- W transposes (one launch) ----
    wt_all_kernel<<<(14336 + 255) / 256, 256, 0, stream>>>(W1, W2, W3, W1T,
                                                           W2T, W3T);

    // ---- layer 1: hA = bf16(x @ W1); hB = A hA ----
    gemm_mfma_kernel<128, 64, false, false, false>
        <<<nb_g, 256, 0, stream>>>(x, W1T, nullptr, hA, N);
    agg64_kernel<<<nb_a, 256, 0, stream>>>(hA, esrc, eno, offs, dinv, hB, N);

    // ---- layer 2: hA = bf16(relu(hB + b1) @ W2); hB = A hA ----
    gemm_mfma_kernel<64, 64, true, true, true>
        <<<nb_g, 256, 0, stream>>>(hB, W2T, b1, hA, N);
    agg64_kernel<<<nb_a, 256, 0, stream>>>(hA, esrc, eno, offs, dinv, hB, N);

    // ---- layer 3: hA = bf16(relu(hB + b2) @ W3); out = A hA + b3; mean ----
    gemm_mfma_kernel<64, 32, true, true, true>
        <<<nb_g, 256, 0, stream>>>(hB, W3T, b2, hA, N);
    agg32_final_kernel<<<nb_a, 256, 0, stream>>>(hA, esrc, eno, offs, dinv,
                                                 b3, out, mean, N);

    // ---- epilogue: fold mean buckets ----
    write_mean_kernel<<<1, 32, 0, stream>>>(mean, out + (size_t)N * 32,
                                            1.0f / (float)N);
}

// Round 9
// 342.500 us; speedup vs baseline: 1.0691x; 1.0691x over previous
//
#include <hip/hip_runtime.h>

// ---------------------------------------------------------------------------
// GCN 3-layer forward on MI355X — radix CSR build + bf16 MFMA GEMMs with
// dinv folded into the GEMM epilogue (hA = dinv * (xW)), so aggregation is
// out[d] = dinv[d] * (sum_e ew*hA[src] + hA[d])  — norm pass ELIMINATED.
// Lessons: R4/R5 random global atomics write through 32B sectors; R8 agg
// FETCH is insensitive to edge payload bytes (table warm dominates), so
// edges stay a single-int2 load (src, ew fp32).
// ---------------------------------------------------------------------------

typedef unsigned int uint32;
typedef __attribute__((ext_vector_type(8))) short bf16x8;
typedef __attribute__((ext_vector_type(4))) float f32x4;

#define G 256          // blocks in pass A / pass B
#define MAXB 512       // max coarse buckets (256-node buckets, N <= 131072)

__device__ __forceinline__ ushort f2bf(float v) {
    uint32 u = __float_as_uint(v);
    u += 0x7fff + ((u >> 16) & 1);  // round to nearest even
    return (ushort)(u >> 16);
}
__device__ __forceinline__ uint32 pack2bf(float a, float b) {
    return (uint32)f2bf(a) | ((uint32)f2bf(b) << 16);
}
__device__ __forceinline__ float bf_lo(uint32 u) {
    return __uint_as_float(u << 16);
}
__device__ __forceinline__ float bf_hi(uint32 u) {
    return __uint_as_float(u & 0xffff0000u);
}

// ---- pass A: per-block LDS histogram over 256-node coarse buckets ----
__global__ __launch_bounds__(1024) void passA_hist_kernel(
    const int* __restrict__ dst, int* __restrict__ histG, int E, int EPB) {
    __shared__ int h[MAXB];
    const int tid = threadIdx.x, g = blockIdx.x;
    if (tid < MAXB) h[tid] = 0;
    __syncthreads();
    const int e0 = g * EPB, e1 = min(e0 + EPB, E);
    for (int e = e0 + tid; e < e1; e += 1024) atomicAdd(&h[dst[e] >> 8], 1);
    __syncthreads();
    if (tid < MAXB) histG[tid * G + g] = h[tid];  // layout [bucket][block]
}

// ---- per-bucket totals (parallel reduce of histG rows) ----
__global__ __launch_bounds__(256) void bucket_total_kernel(
    const int* __restrict__ histG, int* __restrict__ totals) {
    __shared__ int s[256];
    const int b = blockIdx.x, t = threadIdx.x;
    s[t] = histG[b * G + t];
    __syncthreads();
    for (int off = 128; off > 0; off >>= 1) {
        if (t < off) s[t] += s[t + off];
        __syncthreads();
    }
    if (t == 0) totals[b] = s[0];
}

// ---- exclusive scan over bucket totals -> bucketBase[NB+1] (1 block) ----
__global__ __launch_bounds__(512) void bucket_scan_kernel(
    const int* __restrict__ totals, int* __restrict__ bucketBase, int NB,
    int E) {
    __shared__ int s[512];
    const int t = threadIdx.x;
    int v = (t < NB) ? totals[t] : 0;
    s[t] = v;
    __syncthreads();
    for (int off = 1; off < 512; off <<= 1) {
        int u = (t >= off) ? s[t - off] : 0;
        __syncthreads();
        s[t] += u;
        __syncthreads();
    }
    if (t < NB) bucketBase[t] = s[t] - v;  // exclusive
    if (t == 0) bucketBase[NB] = E;
}

// ---- per-(bucket,block) write offsets: scan histG row along blocks ----
__global__ __launch_bounds__(256) void block_offs_kernel(
    const int* __restrict__ histG, const int* __restrict__ bucketBase,
    int* __restrict__ blockOffs) {
    __shared__ int s[G];
    const int b = blockIdx.x, g = threadIdx.x;
    int v = histG[b * G + g];
    s[g] = v;
    __syncthreads();
    for (int off = 1; off < G; off <<= 1) {
        int u = (g >= off) ? s[g - off] : 0;
        __syncthreads();
        s[g] += u;
        __syncthreads();
    }
    blockOffs[b * G + g] = bucketBase[b] + s[g] - v;  // exclusive along g
}

// ---- pass B: scatter edges to their coarse-bucket segment (LDS cursors) ----
__global__ __launch_bounds__(1024) void passB_scatter_kernel(
    const int* __restrict__ src, const int* __restrict__ dst,
    const float* __restrict__ ew, const int* __restrict__ blockOffs,
    int2* __restrict__ tmp, int E, int EPB, int NB) {
    __shared__ int cur[MAXB];
    const int tid = threadIdx.x, g = blockIdx.x;
    if (tid < MAXB) cur[tid] = (tid < NB) ? blockOffs[tid * G + g] : 0;
    __syncthreads();
    const int e0 = g * EPB, e1 = min(e0 + EPB, E);
    for (int e = e0 + tid; e < e1; e += 1024) {
        int d = dst[e];
        int b = d >> 8;
        int pos = atomicAdd(&cur[b], 1);  // LDS atomic
        // pack: src (17 bits) | local-dst (8 bits) << 17 ; .y = ew bits
        tmp[pos] = make_int2(src[e] | ((d & 255) << 17),
                             __float_as_int(ew[e]));
    }
}

// ---- fine: per-bucket LDS counting sort -> edges(src,ew) + offs + dinv ----
__global__ __launch_bounds__(512) void fine_kernel(
    const int2* __restrict__ tmp, const int* __restrict__ bucketBase,
    int* __restrict__ offs, int2* __restrict__ edges,
    float* __restrict__ dinv, int N, int E, int NB) {
    __shared__ int cnt[256];
    __shared__ int pos0[256];
    __shared__ float degf[256];
    const int t = threadIdx.x, b = blockIdx.x;
    const int base = bucketBase[b], endb = bucketBase[b + 1];
    if (t < 256) { cnt[t] = 0; degf[t] = 0.0f; }
    __syncthreads();
    for (int j = base + t; j < endb; j += 512)
        atomicAdd(&cnt[(tmp[j].x >> 17) & 255], 1);
    __syncthreads();
    int v = 0;
    if (t < 256) { v = cnt[t]; pos0[t] = v; }
    __syncthreads();
    for (int off = 1; off < 256; off <<= 1) {  // Hillis-Steele
        int u = 0;
        if (t < 256 && t >= off) u = pos0[t - off];
        __syncthreads();
        if (t < 256) pos0[t] += u;
        __syncthreads();
    }
    if (t < 256) { pos0[t] -= v; cnt[t] = 0; }  // exclusive; reset cursors
    __syncthreads();
    const int node = (b << 8) + t;
    if (t < 256 && node < N) offs[node] = base + pos0[t];
    if (b == NB - 1 && t == 0) offs[N] = E;
    for (int j = base + t; j < endb; j += 512) {
        int2 ed = tmp[j];
        int ldst = (ed.x >> 17) & 255;
        int p = base + pos0[ldst] + atomicAdd(&cnt[ldst], 1);
        edges[p] = make_int2(ed.x & 0x1FFFF, ed.y);  // (src, ew fp32)
        atomicAdd(&degf[ldst], __int_as_float(ed.y));  // LDS float atomic
    }
    __syncthreads();
    if (t < 256 && node < N) dinv[node] = rsqrtf(1.0f + degf[t]);
}

// ---- all W transposes to bf16 in one launch ----
__global__ void wt_all_kernel(const float* __restrict__ W1,
                              const float* __restrict__ W2,
                              const float* __restrict__ W3,
                              ushort* __restrict__ W1T,
                              ushort* __restrict__ W2T,
                              ushort* __restrict__ W3T) {
    int i = blockIdx.x * 256 + threadIdx.x;
    if (i < 8192) {                       // W1: 128x64
        int k = i / 64, m = i % 64;
        W1T[m * 128 + k] = f2bf(W1[i]);
    } else if (i < 12288) {               // W2: 64x64
        int j = i - 8192, k = j / 64, m = j % 64;
        W2T[m * 64 + k] = f2bf(W2[j]);
    } else if (i < 14336) {               // W3: 64x32
        int j = i - 12288, k = j / 32, m = j % 32;
        W3T[m * 64 + k] = f2bf(W3[j]);
    }
}

// ---- MFMA GEMM: out_bf16[n] = dinv[n] * (f(in[n]) @ W).  4 waves x 16-row
// tile, v_mfma_f32_16x16x32_bf16; LDS rows padded +8 bf16. m89 layouts. ----
template <int K, int M, bool RELU, bool BIAS, bool INBF16>
__global__ __launch_bounds__(256) void gemm_mfma_kernel(
    const void* __restrict__ in_, const ushort* __restrict__ WT,
    const float* __restrict__ bias_in, const float* __restrict__ dinv,
    ushort* __restrict__ out, int N) {
    constexpr int KP = K + 8;    // padded LDS row stride (bf16 units)
    constexpr int CCH = M / 16;  // col chunks
    __shared__ __align__(16) ushort Xl[64 * KP];
    __shared__ __align__(16) ushort Wl[M * KP];
    const int tid = threadIdx.x;
    const int node0 = blockIdx.x * 64;

    for (int i = tid; i < M * (K / 8); i += 256) {
        int row = i / (K / 8), kc = i % (K / 8);
        uint4 u = ((const uint4*)WT)[i];
        *(uint4*)&Wl[row * KP + kc * 8] = u;
    }
    if (INBF16) {
        for (int i = tid; i < 64 * (K / 8); i += 256) {
            int row = i / (K / 8), kc = i % (K / 8);
            int node = node0 + row;
            uint4 u = make_uint4(0, 0, 0, 0);
            if (node < N) {
                u = ((const uint4*)in_)[(size_t)node * (K / 8) + kc];
                if (BIAS || RELU) {
                    float v[8];
                    v[0] = bf_lo(u.x); v[1] = bf_hi(u.x);
                    v[2] = bf_lo(u.y); v[3] = bf_hi(u.y);
                    v[4] = bf_lo(u.z); v[5] = bf_hi(u.z);
                    v[6] = bf_lo(u.w); v[7] = bf_hi(u.w);
#pragma unroll
                    for (int j = 0; j < 8; ++j) {
                        if (BIAS) v[j] += bias_in[kc * 8 + j];
                        if (RELU) v[j] = fmaxf(v[j], 0.f);
                    }
                    u.x = pack2bf(v[0], v[1]); u.y = pack2bf(v[2], v[3]);
                    u.z = pack2bf(v[4], v[5]); u.w = pack2bf(v[6], v[7]);
                }
            }
            *(uint4*)&Xl[row * KP + kc * 8] = u;
        }
    } else {
        for (int i = tid; i < 64 * (K / 4); i += 256) {
            int row = i / (K / 4), kc = i % (K / 4);
            int node = node0 + row;
            uint2 p = make_uint2(0, 0);
            if (node < N) {
                float4 v = ((const float4*)in_)[(size_t)node * (K / 4) + kc];
                p.x = pack2bf(v.x, v.y);
                p.y = pack2bf(v.z, v.w);
            }
            *(uint2*)&Xl[row * KP + kc * 4] = p;
        }
    }
    __syncthreads();

    const int wv = tid >> 6, lane = tid & 63;
    const int r16 = lane & 15, quad = lane >> 4;
    f32x4 acc[CCH];
#pragma unroll
    for (int c = 0; c < CCH; ++c) acc[c] = (f32x4){0.f, 0.f, 0.f, 0.f};
#pragma unroll
    for (int kq = 0; kq < K / 32; ++kq) {
        bf16x8 a = *(const bf16x8*)
            &Xl[(wv * 16 + r16) * KP + kq * 32 + quad * 8];
#pragma unroll
        for (int c = 0; c < CCH; ++c) {
            bf16x8 b = *(const bf16x8*)
                &Wl[(c * 16 + r16) * KP + kq * 32 + quad * 8];
            acc[c] = __builtin_amdgcn_mfma_f32_16x16x32_bf16(a, b, acc[c],
                                                             0, 0, 0);
        }
    }
    // D: col = lane&15, row = quad*4 + reg; scale row by dinv[node]
#pragma unroll
    for (int r = 0; r < 4; ++r) {
        int node = node0 + wv * 16 + quad * 4 + r;
        float dv = (node < N) ? dinv[node] : 0.f;
#pragma unroll
        for (int c = 0; c < CCH; ++c) {
            if (node < N)
                out[(size_t)node * M + c * 16 + r16] = f2bf(acc[c][r] * dv);
        }
    }
}

// CSR aggregate, 64-wide bf16 rows (128 B). Wave per node: 8 slots x 8
// uint4-lanes, unroll x2 => 16 rows in flight. out = dinv*(acc + self).
__global__ __launch_bounds__(256) void agg64_kernel(
    const ushort* __restrict__ h, const int2* __restrict__ edges,
    const int* __restrict__ offs, const float* __restrict__ dinv,
    ushort* __restrict__ out, int N) {
    const int wave = threadIdx.x >> 6, lane = threadIdx.x & 63;
    const int node = blockIdx.x * 4 + wave;
    if (node >= N) return;
    const int slot = lane >> 3;  // 0..7
    const int q = lane & 7;      // uint4 index within the 128 B row
    const uint4* __restrict__ h4 = (const uint4*)h;
    const int start = offs[node], end = offs[node + 1];
    float acc[8] = {};
    int j = start + slot;
    for (; j + 8 < end; j += 16) {
        int2 e0 = edges[j];
        int2 e1 = edges[j + 8];
        uint4 u0 = h4[(size_t)e0.x * 8 + q];
        uint4 u1 = h4[(size_t)e1.x * 8 + q];
        float n0 = __int_as_float(e0.y), n1 = __int_as_float(e1.y);
        acc[0] += bf_lo(u0.x) * n0 + bf_lo(u1.x) * n1;
        acc[1] += bf_hi(u0.x) * n0 + bf_hi(u1.x) * n1;
        acc[2] += bf_lo(u0.y) * n0 + bf_lo(u1.y) * n1;
        acc[3] += bf_hi(u0.y) * n0 + bf_hi(u1.y) * n1;
        acc[4] += bf_lo(u0.z) * n0 + bf_lo(u1.z) * n1;
        acc[5] += bf_hi(u0.z) * n0 + bf_hi(u1.z) * n1;
        acc[6] += bf_lo(u0.w) * n0 + bf_lo(u1.w) * n1;
        acc[7] += bf_hi(u0.w) * n0 + bf_hi(u1.w) * n1;
    }
    if (j < end) {
        int2 e0 = edges[j];
        uint4 u0 = h4[(size_t)e0.x * 8 + q];
        float n0 = __int_as_float(e0.y);
        acc[0] += bf_lo(u0.x) * n0; acc[1] += bf_hi(u0.x) * n0;
        acc[2] += bf_lo(u0.y) * n0; acc[3] += bf_hi(u0.y) * n0;
        acc[4] += bf_lo(u0.z) * n0; acc[5] += bf_hi(u0.z) * n0;
        acc[6] += bf_lo(u0.w) * n0; acc[7] += bf_hi(u0.w) * n0;
    }
#pragma unroll
    for (int k = 0; k < 8; ++k) {
        acc[k] += __shfl_xor(acc[k], 8);
        acc[k] += __shfl_xor(acc[k], 16);
        acc[k] += __shfl_xor(acc[k], 32);
    }
    if (slot == 0) {
        float sc = dinv[node];
        uint4 hv = h4[(size_t)node * 8 + q];
        uint4 o;
        o.x = pack2bf((acc[0] + bf_lo(hv.x)) * sc, (acc[1] + bf_hi(hv.x)) * sc);
        o.y = pack2bf((acc[2] + bf_lo(hv.y)) * sc, (acc[3] + bf_hi(hv.y)) * sc);
        o.z = pack2bf((acc[4] + bf_lo(hv.z)) * sc, (acc[5] + bf_hi(hv.z)) * sc);
        o.w = pack2bf((acc[6] + bf_lo(hv.w)) * sc, (acc[7] + bf_hi(hv.w)) * sc);
        ((uint4*)out)[(size_t)node * 8 + q] = o;
    }
}

// CSR aggregate, 32-wide bf16 rows (64 B), final layer. Wave per node:
// 16 slots x 4 lanes. out = dinv*(acc + self) + b3; fp32 d_out; spread mean.
__global__ __launch_bounds__(256) void agg32_final_kernel(
    const ushort* __restrict__ h, const int2* __restrict__ edges,
    const int* __restrict__ offs, const float* __restrict__ dinv,
    const float* __restrict__ b3, float* __restrict__ out,
    float* __restrict__ mean_acc, int N) {
    __shared__ float ssum[32];
    if (threadIdx.x < 32) ssum[threadIdx.x] = 0.0f;
    __syncthreads();
    const int wave = threadIdx.x >> 6, lane = threadIdx.x & 63;
    const int node = blockIdx.x * 4 + wave;
    const int slot = lane >> 2;  // 0..15
    const int q = lane & 3;      // uint4 index within the 64 B row
    const uint4* __restrict__ h4 = (const uint4*)h;
    float acc[8] = {};
    if (node < N) {
        const int start = offs[node], end = offs[node + 1];
        for (int j = start + slot; j < end; j += 16) {
            int2 e0 = edges[j];
            uint4 u0 = h4[(size_t)e0.x * 4 + q];
            float n0 = __int_as_float(e0.y);
            acc[0] += bf_lo(u0.x) * n0; acc[1] += bf_hi(u0.x) * n0;
            acc[2] += bf_lo(u0.y) * n0; acc[3] += bf_hi(u0.y) * n0;
            acc[4] += bf_lo(u0.z) * n0; acc[5] += bf_hi(u0.z) * n0;
            acc[6] += bf_lo(u0.w) * n0; acc[7] += bf_hi(u0.w) * n0;
        }
    }
#pragma unroll
    for (int k = 0; k < 8; ++k) {
        acc[k] += __shfl_xor(acc[k], 4);
        acc[k] += __shfl_xor(acc[k], 8);
        acc[k] += __shfl_xor(acc[k], 16);
        acc[k] += __shfl_xor(acc[k], 32);
    }
    if (node < N && slot == 0) {
        float sc = dinv[node];
        uint4 hv = h4[(size_t)node * 4 + q];
        const float4* b34 = (const float4*)b3;
        float4 bA = b34[q * 2], bB = b34[q * 2 + 1];
        float4 o0, o1;
        o0.x = (acc[0] + bf_lo(hv.x)) * sc + bA.x;
        o0.y = (acc[1] + bf_hi(hv.x)) * sc + bA.y;
        o0.z = (acc[2] + bf_lo(hv.y)) * sc + bA.z;
        o0.w = (acc[3] + bf_hi(hv.y)) * sc + bA.w;
        o1.x = (acc[4] + bf_lo(hv.z)) * sc + bB.x;
        o1.y = (acc[5] + bf_hi(hv.z)) * sc + bB.y;
        o1.z = (acc[6] + bf_lo(hv.w)) * sc + bB.z;
        o1.w = (acc[7] + bf_hi(hv.w)) * sc + bB.w;
        ((float4*)out)[(size_t)node * 8 + q * 2] = o0;
        ((float4*)out)[(size_t)node * 8 + q * 2 + 1] = o1;
        int fb = q * 8;
        atomicAdd(&ssum[fb + 0], o0.x); atomicAdd(&ssum[fb + 1], o0.y);
        atomicAdd(&ssum[fb + 2], o0.z); atomicAdd(&ssum[fb + 3], o0.w);
        atomicAdd(&ssum[fb + 4], o1.x); atomicAdd(&ssum[fb + 5], o1.y);
        atomicAdd(&ssum[fb + 6], o1.z); atomicAdd(&ssum[fb + 7], o1.w);
    }
    __syncthreads();
    if (threadIdx.x < 32) {
        int bucket = blockIdx.x & 127;  // spread-bucket mean (R2 lesson)
        atomicAdd(&mean_acc[bucket * 32 + threadIdx.x], ssum[threadIdx.x]);
    }
}

__global__ void write_mean_kernel(const float* __restrict__ mean_acc,
                                  float* __restrict__ out_tail, float invN) {
    int f = threadIdx.x;
    if (f < 32) {
        float s = 0.0f;
        for (int b = 0; b < 128; ++b) s += mean_acc[b * 32 + f];
        out_tail[f] = s * invN;
    }
}

extern "C" void kernel_launch(void* const* d_in, const int* in_sizes, int n_in,
                              void* d_out, int out_size, void* d_ws,
                              size_t ws_size, hipStream_t stream) {
    const float* x  = (const float*)d_in[0];
    const int*   ei = (const int*)d_in[1];
    const float* ew = (const float*)d_in[2];
    const float* W1 = (const float*)d_in[3];
    const float* b1 = (const float*)d_in[4];
    const float* W2 = (const float*)d_in[5];
    const float* b2 = (const float*)d_in[6];
    const float* W3 = (const float*)d_in[7];
    const float* b3 = (const float*)d_in[8];

    const int N = in_sizes[0] / 128;
    const int E = in_sizes[1] / 2;
    const int* src = ei;
    const int* dst = ei + E;

    const int NB = (N + 255) >> 8;          // 256-node coarse buckets
    const int EPB = (E + G - 1) / G;        // edges per pass-A/B block

    float* out = (float*)d_out;
    char* wsp = (char*)d_ws;
    auto carve = [&](size_t bytes) {
        char* p = wsp;
        wsp += (bytes + 255) & ~(size_t)255;
        return p;
    };
    float*  dinv       = (float*)carve((size_t)N * 4);
    int*    offs       = (int*)carve((size_t)(N + 1) * 4);
    int*    bucketBase = (int*)carve((MAXB + 1) * 4);
    int*    totals     = (int*)carve(MAXB * 4);
    int*    histG      = (int*)carve((size_t)MAXB * G * 4);
    int*    blockOffs  = (int*)carve((size_t)MAXB * G * 4);
    int2*   tmp        = (int2*)carve((size_t)E * 8);
    int2*   edges      = (int2*)carve((size_t)E * 8);
    ushort* hA         = (ushort*)carve((size_t)N * 64 * 2);
    ushort* hB         = (ushort*)carve((size_t)N * 64 * 2);
    ushort* W1T        = (ushort*)carve(128 * 64 * 2);
    ushort* W2T        = (ushort*)carve(64 * 64 * 2);
    ushort* W3T        = (ushort*)carve(64 * 32 * 2);
    float*  mean       = (float*)carve(128 * 32 * 4);

    const int nb_a = (N + 3) / 4;   // wave-per-node kernels: 4 nodes/block
    const int nb_g = (N + 63) / 64; // MFMA gemm: 64 nodes/block

    hipMemsetAsync(mean, 0, 128 * 32 * sizeof(float), stream);

    // ---- CSR build: LDS hist -> totals -> scan -> block offs -> bucket
    //      scatter -> fine counting sort (emits edges/offs/dinv) ----
    passA_hist_kernel<<<G, 1024, 0, stream>>>(dst, histG, E, EPB);
    bucket_total_kernel<<<NB, 256, 0, stream>>>(histG, totals);
    bucket_scan_kernel<<<1, 512, 0, stream>>>(totals, bucketBase, NB, E);
    block_offs_kernel<<<NB, G, 0, stream>>>(histG, bucketBase, blockOffs);
    passB_scatter_kernel<<<G, 1024, 0, stream>>>(src, dst, ew, blockOffs, tmp,
                                                 E, EPB, NB);
    fine_kernel<<<NB, 512, 0, stream>>>(tmp, bucketBase, offs, edges, dinv, N,
                                        E, NB);

    // ---- W transposes (one launch) ----
    wt_all_kernel<<<(14336 + 255) / 256, 256, 0, stream>>>(W1, W2, W3, W1T,
                                                           W2T, W3T);

    // ---- layer 1: hA = bf16(dinv * (x @ W1)); hB = dinv*(A_ew hA + hA) ----
    gemm_mfma_kernel<128, 64, false, false, false>
        <<<nb_g, 256, 0, stream>>>(x, W1T, nullptr, dinv, hA, N);
    agg64_kernel<<<nb_a, 256, 0, stream>>>(hA, edges, offs, dinv, hB, N);

    // ---- layer 2 ----
    gemm_mfma_kernel<64, 64, true, true, true>
        <<<nb_g, 256, 0, stream>>>(hB, W2T, b1, dinv, hA, N);
    agg64_kernel<<<nb_a, 256, 0, stream>>>(hA, edges, offs, dinv, hB, N);

    // ---- layer 3: out = dinv*(A_ew hA3 + hA3) + b3; mean pool ----
    gemm_mfma_kernel<64, 32, true, true, true>
        <<<nb_g, 256, 0, stream>>>(hB, W3T, b2, dinv, hA, N);
    agg32_final_kernel<<<nb_a, 256, 0, stream>>>(hA, edges, offs, dinv, b3,
                                                 out, mean, N);

    // ---- epilogue: fold mean buckets ----
    write_mean_kernel<<<1, 32, 0, stream>>>(mean, out + (size_t)N * 32,
                                            1.0f / (float)N);
}